// Round 1
// baseline (11217.061 us; speedup 1.0000x reference)
//
#include <hip/hip_runtime.h>
#include <math.h>

// Seq2SeqRNN: 2-layer bidirectional GRU encoder (SL=128, BS=64, EE=300, NH=256)
// + 32-step attention decoder (ED=300, V=32000, tied output embedding).
// All math fp32 to keep argmax decisions faithful to the numpy reference.
//
// d_ws layout (~67 MB): embT(300x32000) | enc_out(8192x512) | w1e(8192x300) |
//   W1T | hcat | dec_h ping/pong | h1T | xdec | henc ping/pong | dec_inp
// d_out's first ~32M floats double as encoder scratch (emb, gi0f/b, x1, gi1f/b);
// all dead before decoder step t writes slab t.

#define DINL static __device__ __forceinline__

DINL float sigm(float x) { return 1.0f / (1.0f + expf(-x)); }
DINL float dot4f(float4 a, float4 b) { return a.x*b.x + a.y*b.y + a.z*b.z + a.w*b.w; }

// ---------------- embedding gather: emb[s,b,:] = emb_enc[inp[s,b],:]  (300 = 75 float4)
__global__ __launch_bounds__(256) void k_embed(const float4* __restrict__ E,
                                               const int* __restrict__ inp,
                                               float4* __restrict__ out) {
  int i = blockIdx.x * 256 + threadIdx.x;  // over 8192*75
  if (i >= 8192 * 75) return;
  int row = i / 75, q = i - row * 75;
  out[i] = E[(size_t)inp[row] * 75 + q];
}

// ---------------- transpose: B[c*R + r] = A[r*C + c]
__global__ __launch_bounds__(256) void k_transpose(const float* __restrict__ A,
                                                   float* __restrict__ B, int R, int C) {
  __shared__ float tile[32][33];
  int c0 = blockIdx.x * 32, r0 = blockIdx.y * 32;
  int tx = threadIdx.x & 31, ty = threadIdx.x >> 5;  // 32 x 8
  for (int i = 0; i < 32; i += 8) {
    int r = r0 + ty + i, c = c0 + tx;
    if (r < R && c < C) tile[ty + i][tx] = A[(size_t)r * C + c];
  }
  __syncthreads();
  for (int i = 0; i < 32; i += 8) {
    int c = c0 + ty + i, r = r0 + tx;
    if (c < C && r < R) B[(size_t)c * R + r] = tile[tx][ty + i];
  }
}

// ---------------- generic fp32 GEMM-NT: C[n,m] = sum_k A[n,k]*B[m,k] + bias[m]
// tile 64x64, 256 threads, 4x4 per thread. N must be a multiple of 64.
__global__ __launch_bounds__(256) void k_gemm_nt(const float* __restrict__ A,
                                                 const float* __restrict__ B,
                                                 const float* __restrict__ bias,
                                                 float* __restrict__ C,
                                                 int N, int M, int K) {
  __shared__ float As[16][65];
  __shared__ float Bs[16][65];
  const int tid = threadIdx.x;
  const int bn = blockIdx.x * 64, bm = blockIdx.y * 64;
  const int tn = (tid >> 4) << 2, tm = (tid & 15) << 2;
  float acc[4][4] = {};
  for (int k0 = 0; k0 < K; k0 += 16) {
    for (int i = tid; i < 1024; i += 256) {
      int kk = i & 15, n = i >> 4;
      int gk = k0 + kk;
      As[kk][n] = (gk < K) ? A[(size_t)(bn + n) * K + gk] : 0.0f;
      Bs[kk][n] = (gk < K && (bm + n) < M) ? B[(size_t)(bm + n) * K + gk] : 0.0f;
    }
    __syncthreads();
#pragma unroll
    for (int kk = 0; kk < 16; ++kk) {
      float a[4], bb[4];
#pragma unroll
      for (int i = 0; i < 4; ++i) a[i] = As[kk][tn + i];
#pragma unroll
      for (int j = 0; j < 4; ++j) bb[j] = Bs[kk][tm + j];
#pragma unroll
      for (int i = 0; i < 4; ++i)
#pragma unroll
        for (int j = 0; j < 4; ++j) acc[i][j] += a[i] * bb[j];
    }
    __syncthreads();
  }
#pragma unroll
  for (int i = 0; i < 4; ++i) {
    int row = bn + tn + i;
#pragma unroll
    for (int j = 0; j < 4; ++j) {
      int col = bm + tm + j;
      if (row < N && col < M)
        C[(size_t)row * M + col] = acc[i][j] + (bias ? bias[col] : 0.0f);
    }
  }
}

// ---------------- one encoder GRU timestep, both directions fused.
// block = 256 (16 h-cols x 16 batches); grid (16 colchunks, 4 batchchunks, 2 dirs).
// Each thread owns one (b, hcol): computes the r/z/n gh triplet (self-contained).
__global__ __launch_bounds__(256) void k_enc_step(
    const float* __restrict__ giF, const float* __restrict__ giB,
    const float* __restrict__ hinF, const float* __restrict__ hinB,
    float* __restrict__ houtF, float* __restrict__ houtB,
    const float* __restrict__ WhhF, const float* __restrict__ WhhB,
    const float* __restrict__ bhhF, const float* __restrict__ bhhB,
    float* __restrict__ yF, float* __restrict__ yB) {
  const int dir = blockIdx.z;
  const float* gi = dir ? giB : giF;
  const float* hin = dir ? hinB : hinF;
  float* hout = dir ? houtB : houtF;
  const float* Whh = dir ? WhhB : WhhF;
  const float* bhh = dir ? bhhB : bhhF;
  float* y = dir ? yB : yF;
  const int ycol = dir ? 256 : 0;

  const int c0 = blockIdx.x * 16;
  const int b0 = blockIdx.y * 16;
  const int tid = threadIdx.x;
  const int cl = tid & 15, bl = tid >> 4;

  __shared__ __align__(16) float Wlds[3][16][260];  // pad 260 to break bank conflicts
  for (int i = tid; i < 48 * 64; i += 256) {
    int row = i >> 6, q = i & 63;
    int g = row >> 4, rc = row & 15;
    float4 w = ((const float4*)Whh)[(size_t)(c0 + rc + (g << 8)) * 64 + q];
    *(float4*)&Wlds[g][rc][q << 2] = w;
  }
  __syncthreads();

  const int b = b0 + bl;
  const int c = c0 + cl;
  const float* hrow = hin + (b << 8);
  float ar = 0.f, az = 0.f, an = 0.f;
#pragma unroll 4
  for (int k = 0; k < 256; k += 4) {
    float4 hv = *(const float4*)(hrow + k);
    float4 wr = *(const float4*)&Wlds[0][cl][k];
    float4 wz = *(const float4*)&Wlds[1][cl][k];
    float4 wn = *(const float4*)&Wlds[2][cl][k];
    ar += dot4f(hv, wr);
    az += dot4f(hv, wz);
    an += dot4f(hv, wn);
  }
  float ghr = ar + bhh[c], ghz = az + bhh[256 + c], ghn = an + bhh[512 + c];
  const float* gir = gi + (size_t)b * 768;
  float r = sigm(gir[c] + ghr);
  float z = sigm(gir[256 + c] + ghz);
  float n = tanhf(gir[512 + c] + r * ghn);
  float hold = hrow[c];
  float hnew = (1.f - z) * n + z * hold;
  hout[(b << 8) + c] = hnew;
  y[(b << 9) + ycol + c] = hnew;
}

// ---------------- build hcat[2][64][512] = [ [yf0[127],yb0[0]], [yf1[127],yb1[0]] ]
__global__ __launch_bounds__(256) void k_hcat(const float* __restrict__ x1,
                                              const float* __restrict__ encout,
                                              float* __restrict__ hcat) {
  int i = blockIdx.x * 256 + threadIdx.x;  // 65536
  int l = i >> 15, r = i & 32767, b = r >> 9, d = r & 511;
  const float* src = l ? encout : x1;
  int ts = (d < 256) ? 127 : 0;
  hcat[i] = src[((size_t)(ts << 6) + b) * 512 + d];
}

// ---------------- decoder attention block: one WG per batch b.
// w2h = h1[b]@l2W.T+l2b ; scores = tanh(w1e+w2h)@Vatt ; softmax over s ;
// Xa = sum_s a*enc_out ; x = [e,Xa]@l3W.T+l3b  -> xdec[b]
__global__ __launch_bounds__(256) void k_dec_att(
    const float* __restrict__ h1, const float* __restrict__ w1e,
    const float* __restrict__ encout,
    const float* __restrict__ l2W, const float* __restrict__ l2b,
    const float* __restrict__ l3W, const float* __restrict__ l3b,
    const float* __restrict__ Vatt, const float* __restrict__ embdec,
    const int* __restrict__ decin, float* __restrict__ xdec) {
  const int b = blockIdx.x, tid = threadIdx.x;
  __shared__ __align__(16) float h1s[300];
  __shared__ __align__(16) float w2h[300];
  __shared__ __align__(16) float eXa[812];
  __shared__ float aa[128];
  __shared__ float red[128];

  for (int i = tid; i < 300; i += 256) h1s[i] = h1[b * 300 + i];
  __syncthreads();

  for (int m = tid; m < 300; m += 256) {
    const float4* wr = (const float4*)(l2W + (size_t)m * 300);
    const float4* hr = (const float4*)h1s;
    float acc = l2b[m];
    for (int q = 0; q < 75; ++q) acc += dot4f(wr[q], hr[q]);
    w2h[m] = acc;
  }
  __syncthreads();

  if (tid < 128) {
    const float4* wp = (const float4*)(w1e + ((size_t)(tid << 6) + b) * 300);
    const float4* vp = (const float4*)Vatt;
    const float4* hp = (const float4*)w2h;
    float acc = 0.f;
    for (int q = 0; q < 75; ++q) {
      float4 w = wp[q], h = hp[q], v = vp[q];
      acc += tanhf(w.x + h.x) * v.x + tanhf(w.y + h.y) * v.y +
             tanhf(w.z + h.z) * v.z + tanhf(w.w + h.w) * v.w;
    }
    aa[tid] = acc;
    red[tid] = acc;
  }
  __syncthreads();
  for (int s = 64; s > 0; s >>= 1) {
    if (tid < s) red[tid] = fmaxf(red[tid], red[tid + s]);
    __syncthreads();
  }
  float mx = red[0];
  __syncthreads();
  if (tid < 128) {
    float ex = expf(aa[tid] - mx);
    aa[tid] = ex;
    red[tid] = ex;
  }
  __syncthreads();
  for (int s = 64; s > 0; s >>= 1) {
    if (tid < s) red[tid] += red[tid + s];
    __syncthreads();
  }
  float inv = 1.0f / red[0];
  __syncthreads();
  if (tid < 128) aa[tid] *= inv;
  int ib = decin[b];
  for (int d = tid; d < 300; d += 256) eXa[d] = embdec[(size_t)ib * 300 + d];
  __syncthreads();  // aa + e ready

  for (int d = tid; d < 512; d += 256) {
    float acc = 0.f;
    for (int s = 0; s < 128; ++s) acc += aa[s] * encout[((size_t)(s << 6) + b) * 512 + d];
    eXa[300 + d] = acc;
  }
  __syncthreads();

  for (int m = tid; m < 300; m += 256) {
    const float4* wr = (const float4*)(l3W + (size_t)m * 812);
    const float4* xr = (const float4*)eXa;
    float acc = l3b[m];
    for (int q = 0; q < 203; ++q) acc += dot4f(wr[q], xr[q]);
    xdec[b * 300 + m] = acc;
  }
}

// ---------------- decoder GRU cell (300/300). block 256 = 16c x 16b, grid (19,4).
__global__ __launch_bounds__(256) void k_gru300(
    const float* __restrict__ xin, const float* __restrict__ hin,
    float* __restrict__ hout, float* __restrict__ houtT,
    const float* __restrict__ Wih, const float* __restrict__ Whh,
    const float* __restrict__ bih, const float* __restrict__ bhh) {
  const int tid = threadIdx.x;
  const int cl = tid & 15, bl = tid >> 4;
  const int c = blockIdx.x * 16 + cl;
  const int b0 = blockIdx.y * 16;
  const int b = b0 + bl;
  __shared__ __align__(16) float xs[16][300];
  __shared__ __align__(16) float hs[16][300];
  for (int i = tid; i < 16 * 75; i += 256) {
    int row = i / 75, q = i - row * 75;
    ((float4*)&xs[row][0])[q] = ((const float4*)(xin + (size_t)(b0 + row) * 300))[q];
    ((float4*)&hs[row][0])[q] = ((const float4*)(hin + (size_t)(b0 + row) * 300))[q];
  }
  __syncthreads();
  if (c < 300) {
    float gir = bih[c], giz = bih[300 + c], gin = bih[600 + c];
    float ghr = bhh[c], ghz = bhh[300 + c], ghn = bhh[600 + c];
    const float4* wir = (const float4*)(Wih + (size_t)c * 300);
    const float4* wiz = (const float4*)(Wih + (size_t)(300 + c) * 300);
    const float4* win = (const float4*)(Wih + (size_t)(600 + c) * 300);
    const float4* whr = (const float4*)(Whh + (size_t)c * 300);
    const float4* whz = (const float4*)(Whh + (size_t)(300 + c) * 300);
    const float4* whn = (const float4*)(Whh + (size_t)(600 + c) * 300);
    const float4* xr = (const float4*)&xs[bl][0];
    const float4* hr = (const float4*)&hs[bl][0];
    for (int q = 0; q < 75; ++q) {
      float4 xv = xr[q], hv = hr[q];
      gir += dot4f(xv, wir[q]);
      giz += dot4f(xv, wiz[q]);
      gin += dot4f(xv, win[q]);
      ghr += dot4f(hv, whr[q]);
      ghz += dot4f(hv, whz[q]);
      ghn += dot4f(hv, whn[q]);
    }
    float r = sigm(gir + ghr), z = sigm(giz + ghz);
    float n = tanhf(gin + r * ghn);
    float hnew = (1.f - z) * n + z * hs[bl][c];
    hout[(size_t)b * 300 + c] = hnew;
    if (houtT) houtT[(size_t)c * 64 + b] = hnew;
  }
}

// ---------------- logits: out[b,v] = h1 . embT[:,v] + out_b[v].
// thread per v (coalesced embT), 32 batches per thread (h1T scalar/broadcast loads).
__global__ __launch_bounds__(256) void k_dec_out(const float* __restrict__ embT,
                                                 const float* __restrict__ h1T,
                                                 const float* __restrict__ outb,
                                                 float* __restrict__ out) {
  const int v = blockIdx.x * 256 + threadIdx.x;  // 125 blocks * 256 = 32000
  const int bh = blockIdx.y;                      // batch half
  const float* h = h1T + bh * 32;
  float acc[32];
#pragma unroll
  for (int i = 0; i < 32; ++i) acc[i] = 0.f;
  for (int k = 0; k < 300; ++k) {
    float ev = embT[(size_t)k * 32000 + v];
#pragma unroll
    for (int i = 0; i < 32; ++i) acc[i] += ev * h[(size_t)k * 64 + i];
  }
  float bo = outb[v];
#pragma unroll
  for (int i = 0; i < 32; ++i) out[(size_t)(bh * 32 + i) * 32000 + v] = acc[i] + bo;
}

// ---------------- argmax per batch row, first-index tie rule (matches jnp.argmax)
__global__ __launch_bounds__(256) void k_argmax(const float* __restrict__ out,
                                                int* __restrict__ decin) {
  const int b = blockIdx.x, tid = threadIdx.x;
  const float* row = out + (size_t)b * 32000;
  float best = -INFINITY;
  int bi = 0;
  for (int v = tid; v < 32000; v += 256) {
    float x = row[v];
    if (x > best) { best = x; bi = v; }
  }
  __shared__ float bv[256];
  __shared__ int bidx[256];
  bv[tid] = best;
  bidx[tid] = bi;
  __syncthreads();
  for (int s = 128; s > 0; s >>= 1) {
    if (tid < s) {
      if (bv[tid + s] > bv[tid] || (bv[tid + s] == bv[tid] && bidx[tid + s] < bidx[tid])) {
        bv[tid] = bv[tid + s];
        bidx[tid] = bidx[tid + s];
      }
    }
    __syncthreads();
  }
  if (tid == 0) decin[b] = bidx[0];
}

extern "C" void kernel_launch(void* const* d_in, const int* in_sizes, int n_in,
                              void* d_out_v, int out_size, void* d_ws, size_t ws_size,
                              hipStream_t stream) {
  (void)in_sizes; (void)n_in; (void)out_size; (void)ws_size;
  const float* emb_enc = (const float*)d_in[0];
  const float* eWih0   = (const float*)d_in[1];
  const float* eWhh0   = (const float*)d_in[2];
  const float* ebih0   = (const float*)d_in[3];
  const float* ebhh0   = (const float*)d_in[4];
  const float* eWih1   = (const float*)d_in[5];
  const float* eWhh1   = (const float*)d_in[6];
  const float* ebih1   = (const float*)d_in[7];
  const float* ebhh1   = (const float*)d_in[8];
  const float* Wout    = (const float*)d_in[9];
  const float* emb_dec = (const float*)d_in[10];
  const float* dWih    = (const float*)d_in[11];
  const float* dWhh    = (const float*)d_in[12];
  const float* dbih    = (const float*)d_in[13];
  const float* dbhh    = (const float*)d_in[14];
  const float* W1      = (const float*)d_in[15];
  const float* l2W     = (const float*)d_in[16];
  const float* l2b     = (const float*)d_in[17];
  const float* l3W     = (const float*)d_in[18];
  const float* l3b     = (const float*)d_in[19];
  const float* Vatt    = (const float*)d_in[20];
  const float* outb    = (const float*)d_in[21];
  const int* inp       = (const int*)d_in[22];
  float* d_out = (float*)d_out_v;

  // ---- workspace carve (~67 MB)
  float* ws = (float*)d_ws;
  size_t off = 0;
  auto take = [&](size_t n) { float* p = ws + off; off += (n + 3) & ~(size_t)3; return p; };
  float* embT   = take((size_t)300 * 32000);
  float* encout = take((size_t)8192 * 512);
  float* w1e    = take((size_t)8192 * 300);
  float* W1T    = take((size_t)300 * 512);
  float* hcat   = take((size_t)128 * 512);
  float* dech   = take((size_t)2 * 2 * 64 * 300);  // ping-pong [2][2][64][300]
  float* h1T    = take((size_t)300 * 64);
  float* xdec   = take((size_t)64 * 300);
  float* henc   = take((size_t)4 * 64 * 256);      // [pp][dir] 4 x 16384
  int* decin    = (int*)take(64);

  // ---- encoder-phase scratch inside d_out (dead before decoder writes)
  float* emb  = d_out;              // 2,457,600
  float* gi0f = emb + 2457600;      // 6,291,456
  float* gi0b = gi0f + 6291456;
  float* x1   = gi0b + 6291456;     // 4,194,304
  float* gi1f = x1 + 4194304;
  float* gi1b = gi1f + 6291456;     // total 31.8M < 65.5M floats

  // ---- embeddings & transposes
  k_embed<<<2400, 256, 0, stream>>>((const float4*)emb_enc, inp, (float4*)emb);
  k_transpose<<<dim3(10, 16), 256, 0, stream>>>(W1, W1T, 512, 300);
  k_transpose<<<dim3(10, 1000), 256, 0, stream>>>(emb_dec, embT, 32000, 300);

  // ---- encoder layer 0
  k_gemm_nt<<<dim3(128, 12), 256, 0, stream>>>(emb, eWih0, ebih0, gi0f, 8192, 768, 300);
  k_gemm_nt<<<dim3(128, 12), 256, 0, stream>>>(emb, eWih0 + 230400, ebih0 + 768, gi0b, 8192, 768, 300);
  hipMemsetAsync(henc, 0, 4 * 64 * 256 * sizeof(float), stream);
  for (int t = 0; t < 128; ++t) {
    int tb = 127 - t, pp = t & 1, np = pp ^ 1;
    k_enc_step<<<dim3(16, 4, 2), 256, 0, stream>>>(
        gi0f + (size_t)t * 49152, gi0b + (size_t)tb * 49152,
        henc + (pp * 2 + 0) * 16384, henc + (pp * 2 + 1) * 16384,
        henc + (np * 2 + 0) * 16384, henc + (np * 2 + 1) * 16384,
        eWhh0, eWhh0 + 196608, ebhh0, ebhh0 + 768,
        x1 + (size_t)t * 32768, x1 + (size_t)tb * 32768);
  }

  // ---- encoder layer 1
  k_gemm_nt<<<dim3(128, 12), 256, 0, stream>>>(x1, eWih1, ebih1, gi1f, 8192, 768, 512);
  k_gemm_nt<<<dim3(128, 12), 256, 0, stream>>>(x1, eWih1 + 393216, ebih1 + 768, gi1b, 8192, 768, 512);
  hipMemsetAsync(henc, 0, 4 * 64 * 256 * sizeof(float), stream);
  for (int t = 0; t < 128; ++t) {
    int tb = 127 - t, pp = t & 1, np = pp ^ 1;
    k_enc_step<<<dim3(16, 4, 2), 256, 0, stream>>>(
        gi1f + (size_t)t * 49152, gi1b + (size_t)tb * 49152,
        henc + (pp * 2 + 0) * 16384, henc + (pp * 2 + 1) * 16384,
        henc + (np * 2 + 0) * 16384, henc + (np * 2 + 1) * 16384,
        eWhh1, eWhh1 + 196608, ebhh1, ebhh1 + 768,
        encout + (size_t)t * 32768, encout + (size_t)tb * 32768);
  }

  // ---- encoder epilogue: h projection + w1e
  k_hcat<<<256, 256, 0, stream>>>(x1, encout, hcat);
  k_gemm_nt<<<dim3(2, 5), 256, 0, stream>>>(hcat, Wout, nullptr, dech, 128, 300, 512);
  k_gemm_nt<<<dim3(128, 5), 256, 0, stream>>>(encout, W1T, nullptr, w1e, 8192, 300, 512);

  // ---- decoder
  hipMemsetAsync(decin, 0, 64 * sizeof(int), stream);
  for (int t = 0; t < 32; ++t) {
    int cur = t & 1, nxt = cur ^ 1;
    float* hc = dech + cur * 38400;
    float* hn = dech + nxt * 38400;
    k_dec_att<<<64, 256, 0, stream>>>(hc + 19200, w1e, encout, l2W, l2b, l3W, l3b,
                                      Vatt, emb_dec, decin, xdec);
    k_gru300<<<dim3(19, 4), 256, 0, stream>>>(xdec, hc, hn, nullptr,
                                              dWih, dWhh, dbih, dbhh);
    k_gru300<<<dim3(19, 4), 256, 0, stream>>>(hn, hc + 19200, hn + 19200, h1T,
                                              dWih + 270000, dWhh + 270000,
                                              dbih + 900, dbhh + 900);
    k_dec_out<<<dim3(125, 2), 256, 0, stream>>>(embT, h1T, outb,
                                                d_out + (size_t)t * 2048000);
    k_argmax<<<64, 256, 0, stream>>>(d_out + (size_t)t * 2048000, decin);
  }
}

// Round 2
// 10343.950 us; speedup vs baseline: 1.0844x; 1.0844x over previous
//
#include <hip/hip_runtime.h>
#include <math.h>

// Seq2SeqRNN fp32: persistent-encoder version.
// Encoder recurrence: ONE kernel per layer (128 co-resident WGs, Whh in LDS once,
// sub-group spin barriers between timesteps). GEMMs: 128x128 tile, BK=8, float4.
// Decoder: 4 kernels/step; argmax fused into the logit kernel via packed u64 max.

#define DINL static __device__ __forceinline__

DINL float sigm(float x) { return 1.0f / (1.0f + expf(-x)); }
DINL float dot4f(float4 a, float4 b) { return a.x*b.x + a.y*b.y + a.z*b.z + a.w*b.w; }

DINL unsigned long long packmax(float x, int v) {
  unsigned u = __float_as_uint(x);
  u = (u & 0x80000000u) ? ~u : (u | 0x80000000u);
  return ((unsigned long long)u << 32) | (unsigned)(~v);  // ties -> smaller v wins
}
DINL unsigned long long umax64(unsigned long long a, unsigned long long b) {
  return a > b ? a : b;
}

// ---------------- embedding gather (300 = 75 float4)
__global__ __launch_bounds__(256) void k_embed(const float4* __restrict__ E,
                                               const int* __restrict__ inp,
                                               float4* __restrict__ out) {
  int i = blockIdx.x * 256 + threadIdx.x;
  if (i >= 8192 * 75) return;
  int row = i / 75, q = i - row * 75;
  out[i] = E[(size_t)inp[row] * 75 + q];
}

// ---------------- transpose B[c*R+r] = A[r*C+c]
__global__ __launch_bounds__(256) void k_transpose(const float* __restrict__ A,
                                                   float* __restrict__ B, int R, int C) {
  __shared__ float tile[32][33];
  int c0 = blockIdx.x * 32, r0 = blockIdx.y * 32;
  int tx = threadIdx.x & 31, ty = threadIdx.x >> 5;
  for (int i = 0; i < 32; i += 8) {
    int r = r0 + ty + i, c = c0 + tx;
    if (r < R && c < C) tile[ty + i][tx] = A[(size_t)r * C + c];
  }
  __syncthreads();
  for (int i = 0; i < 32; i += 8) {
    int c = c0 + ty + i, r = r0 + tx;
    if (c < C && r < R) B[(size_t)c * R + r] = tile[tx][ty + i];
  }
}

// ---------------- fp32 GEMM-NT: C[n,m] = sum_k A[n,k]*B[m,k] + bias[m]
// 128x128 tile, BK=8, 256 threads, 8x8 per thread. N multiple of 128.
__global__ __launch_bounds__(256) void k_gemm128(const float* __restrict__ A,
                                                 const float* __restrict__ B,
                                                 const float* __restrict__ bias,
                                                 float* __restrict__ C,
                                                 int N, int M, int K) {
  __shared__ float As[8][132];
  __shared__ float Bs[8][132];
  const int tid = threadIdx.x;
  const int bn = blockIdx.x * 128, bm = blockIdx.y * 128;
  const int tn = (tid >> 4) << 3, tm = (tid & 15) << 3;
  const int r = tid & 127;
  const bool isB = tid >= 128;
  const float* src = isB ? (B + (size_t)(bm + r) * K) : (A + (size_t)(bn + r) * K);
  const bool rowok = isB ? (bm + r < M) : (bn + r < N);
  float acc[8][8] = {};
  for (int k0 = 0; k0 < K; k0 += 8) {
    float v[8];
    if (rowok && k0 + 8 <= K) {
      float4 p0 = *(const float4*)(src + k0);
      float4 p1 = *(const float4*)(src + k0 + 4);
      v[0]=p0.x; v[1]=p0.y; v[2]=p0.z; v[3]=p0.w;
      v[4]=p1.x; v[5]=p1.y; v[6]=p1.z; v[7]=p1.w;
    } else {
#pragma unroll
      for (int j = 0; j < 8; ++j) v[j] = (rowok && k0 + j < K) ? src[k0 + j] : 0.0f;
    }
    float (*dst)[132] = isB ? Bs : As;
#pragma unroll
    for (int j = 0; j < 8; ++j) dst[j][r] = v[j];
    __syncthreads();
#pragma unroll
    for (int kk = 0; kk < 8; ++kk) {
      float a[8], b[8];
      *(float4*)&a[0] = *(const float4*)&As[kk][tn];
      *(float4*)&a[4] = *(const float4*)&As[kk][tn + 4];
      *(float4*)&b[0] = *(const float4*)&Bs[kk][tm];
      *(float4*)&b[4] = *(const float4*)&Bs[kk][tm + 4];
#pragma unroll
      for (int i = 0; i < 8; ++i)
#pragma unroll
        for (int j = 0; j < 8; ++j) acc[i][j] += a[i] * b[j];
    }
    __syncthreads();
  }
#pragma unroll
  for (int i = 0; i < 8; ++i) {
    int row = bn + tn + i;
    if (row >= N) continue;
#pragma unroll
    for (int j = 0; j < 8; ++j) {
      int col = bm + tm + j;
      if (col < M) C[(size_t)row * M + col] = acc[i][j] + (bias ? bias[col] : 0.0f);
    }
  }
}

// ---------------- persistent encoder layer: all 128 timesteps in one dispatch.
// grid (16 cchunks, 4 bchunks, 2 dirs) = 128 WGs of 256 (<=256 CUs, co-resident).
// Whh slice staged in LDS once. Sub-group barrier = 16 WGs sharing (dir,bchunk).
__global__ __launch_bounds__(256) void k_enc_layer(
    const float* __restrict__ giF, const float* __restrict__ giB,
    const float* __restrict__ Whh,   // [2][768][256]
    const float* __restrict__ bhh,   // [2][768]
    float* __restrict__ y,           // [128][64][512], dir -> col offset
    float* __restrict__ hbuf,        // [2 pp][2 dir][64][256]
    int* __restrict__ bar) {         // [8 groups][128]
  const int dir = blockIdx.z;
  const int c0 = blockIdx.x * 16, b0 = blockIdx.y * 16;
  const int tid = threadIdx.x, cl = tid & 15, bl = tid >> 4;
  const float* gi = dir ? giB : giF;
  const float* W = Whh + (size_t)dir * 196608;
  const float* bh = bhh + dir * 768;
  float* hb = hbuf + dir * 16384;
  int* mybar = bar + (dir * 4 + blockIdx.y) * 128;

  __shared__ __align__(16) float Wlds[3][16][260];
  for (int i = tid; i < 48 * 64; i += 256) {
    int row = i >> 6, q = i & 63;
    int g = row >> 4, rc = row & 15;
    float4 w = ((const float4*)W)[(size_t)(c0 + rc + (g << 8)) * 64 + q];
    *(float4*)&Wlds[g][rc][q << 2] = w;
  }
  __syncthreads();

  const int b = b0 + bl, c = c0 + cl;
  const float bhr = bh[c], bhz = bh[256 + c], bhn = bh[512 + c];

  for (int t = 0; t < 128; ++t) {
    const int tt = dir ? 127 - t : t;
    const int pp = t & 1;
    const float* hrow = hb + pp * 32768 + (b << 8);
    float ar = 0.f, az = 0.f, an = 0.f;
#pragma unroll 4
    for (int k = 0; k < 256; k += 4) {
      float4 hv = *(const float4*)(hrow + k);
      float4 wr = *(const float4*)&Wlds[0][cl][k];
      float4 wz = *(const float4*)&Wlds[1][cl][k];
      float4 wn = *(const float4*)&Wlds[2][cl][k];
      ar += dot4f(hv, wr);
      az += dot4f(hv, wz);
      an += dot4f(hv, wn);
    }
    const float* gir = gi + (size_t)tt * 49152 + (size_t)b * 768;
    float rg = sigm(gir[c] + ar + bhr);
    float zg = sigm(gir[256 + c] + az + bhz);
    float ng = tanhf(gir[512 + c] + rg * (an + bhn));
    float hnew = (1.f - zg) * ng + zg * hrow[c];
    hb[(pp ^ 1) * 32768 + (b << 8) + c] = hnew;
    y[(size_t)tt * 32768 + (b << 9) + (dir << 8) + c] = hnew;

    if (t < 127) {
      __syncthreads();  // all writes of this WG issued
      if (tid == 0) {
        __hip_atomic_fetch_add(&mybar[t], 1, __ATOMIC_RELEASE, __HIP_MEMORY_SCOPE_AGENT);
        while (__hip_atomic_load(&mybar[t], __ATOMIC_ACQUIRE, __HIP_MEMORY_SCOPE_AGENT) < 16)
          __builtin_amdgcn_s_sleep(1);
      }
      __syncthreads();
    }
  }
}

// ---------------- hcat[2][64][512]
__global__ __launch_bounds__(256) void k_hcat(const float* __restrict__ x1,
                                              const float* __restrict__ encout,
                                              float* __restrict__ hcat) {
  int i = blockIdx.x * 256 + threadIdx.x;  // 65536
  int l = i >> 15, r = i & 32767, b = r >> 9, d = r & 511;
  const float* src = l ? encout : x1;
  int ts = (d < 256) ? 127 : 0;
  hcat[i] = src[((size_t)(ts << 6) + b) * 512 + d];
}

// ---------------- decoder attention + x build; also decodes prev argmax from bests.
__global__ __launch_bounds__(256) void k_dec_att(
    const float* __restrict__ h1, const float* __restrict__ w1e,
    const float* __restrict__ encout,
    const float* __restrict__ l2W, const float* __restrict__ l2b,
    const float* __restrict__ l3W, const float* __restrict__ l3b,
    const float* __restrict__ Vatt, const float* __restrict__ embdec,
    const unsigned long long* __restrict__ prev,  // [125][64] or null (step 0)
    float* __restrict__ xdec) {
  const int b = blockIdx.x, tid = threadIdx.x;
  __shared__ __align__(16) float h1s[300];
  __shared__ __align__(16) float w2h[300];
  __shared__ __align__(16) float eXa[812];
  __shared__ float aa[128];
  __shared__ float red[128];
  __shared__ unsigned long long redb[128];

  // decode previous token for this batch
  if (tid < 128) redb[tid] = (prev && tid < 125) ? prev[(size_t)tid * 64 + b] : 0ULL;
  for (int i = tid; i < 300; i += 256) h1s[i] = h1[b * 300 + i];
  __syncthreads();
  for (int s = 64; s > 0; s >>= 1) {
    if (tid < s) redb[tid] = umax64(redb[tid], redb[tid + s]);
    __syncthreads();
  }
  const int ib = prev ? (int)(~(unsigned)(redb[0] & 0xFFFFFFFFULL)) : 0;

  for (int m = tid; m < 300; m += 256) {
    const float4* wr = (const float4*)(l2W + (size_t)m * 300);
    const float4* hr = (const float4*)h1s;
    float acc = l2b[m];
    for (int q = 0; q < 75; ++q) acc += dot4f(wr[q], hr[q]);
    w2h[m] = acc;
  }
  __syncthreads();

  if (tid < 128) {
    const float4* wp = (const float4*)(w1e + ((size_t)(tid << 6) + b) * 300);
    const float4* vp = (const float4*)Vatt;
    const float4* hp = (const float4*)w2h;
    float acc = 0.f;
    for (int q = 0; q < 75; ++q) {
      float4 w = wp[q], h = hp[q], v = vp[q];
      acc += tanhf(w.x + h.x) * v.x + tanhf(w.y + h.y) * v.y +
             tanhf(w.z + h.z) * v.z + tanhf(w.w + h.w) * v.w;
    }
    aa[tid] = acc;
    red[tid] = acc;
  }
  __syncthreads();
  for (int s = 64; s > 0; s >>= 1) {
    if (tid < s) red[tid] = fmaxf(red[tid], red[tid + s]);
    __syncthreads();
  }
  float mx = red[0];
  __syncthreads();
  if (tid < 128) {
    float ex = expf(aa[tid] - mx);
    aa[tid] = ex;
    red[tid] = ex;
  }
  __syncthreads();
  for (int s = 64; s > 0; s >>= 1) {
    if (tid < s) red[tid] += red[tid + s];
    __syncthreads();
  }
  float inv = 1.0f / red[0];
  __syncthreads();
  if (tid < 128) aa[tid] *= inv;
  for (int d = tid; d < 300; d += 256) eXa[d] = embdec[(size_t)ib * 300 + d];
  __syncthreads();

  for (int d = tid; d < 512; d += 256) {
    float acc = 0.f;
    for (int s = 0; s < 128; ++s) acc += aa[s] * encout[((size_t)(s << 6) + b) * 512 + d];
    eXa[300 + d] = acc;
  }
  __syncthreads();

  for (int m = tid; m < 300; m += 256) {
    const float4* wr = (const float4*)(l3W + (size_t)m * 812);
    const float4* xr = (const float4*)eXa;
    float acc = l3b[m];
    for (int q = 0; q < 203; ++q) acc += dot4f(wr[q], xr[q]);
    xdec[b * 300 + m] = acc;
  }
}

// ---------------- decoder GRU cell (300/300)
__global__ __launch_bounds__(256) void k_gru300(
    const float* __restrict__ xin, const float* __restrict__ hin,
    float* __restrict__ hout, float* __restrict__ houtT,
    const float* __restrict__ Wih, const float* __restrict__ Whh,
    const float* __restrict__ bih, const float* __restrict__ bhh) {
  const int tid = threadIdx.x;
  const int cl = tid & 15, bl = tid >> 4;
  const int c = blockIdx.x * 16 + cl;
  const int b0 = blockIdx.y * 16;
  const int b = b0 + bl;
  __shared__ __align__(16) float xs[16][300];
  __shared__ __align__(16) float hs[16][300];
  for (int i = tid; i < 16 * 75; i += 256) {
    int row = i / 75, q = i - row * 75;
    ((float4*)&xs[row][0])[q] = ((const float4*)(xin + (size_t)(b0 + row) * 300))[q];
    ((float4*)&hs[row][0])[q] = ((const float4*)(hin + (size_t)(b0 + row) * 300))[q];
  }
  __syncthreads();
  if (c < 300) {
    float gir = bih[c], giz = bih[300 + c], gin = bih[600 + c];
    float ghr = bhh[c], ghz = bhh[300 + c], ghn = bhh[600 + c];
    const float4* wir = (const float4*)(Wih + (size_t)c * 300);
    const float4* wiz = (const float4*)(Wih + (size_t)(300 + c) * 300);
    const float4* win = (const float4*)(Wih + (size_t)(600 + c) * 300);
    const float4* whr = (const float4*)(Whh + (size_t)c * 300);
    const float4* whz = (const float4*)(Whh + (size_t)(300 + c) * 300);
    const float4* whn = (const float4*)(Whh + (size_t)(600 + c) * 300);
    const float4* xr = (const float4*)&xs[bl][0];
    const float4* hr = (const float4*)&hs[bl][0];
    for (int q = 0; q < 75; ++q) {
      float4 xv = xr[q], hv = hr[q];
      gir += dot4f(xv, wir[q]);
      giz += dot4f(xv, wiz[q]);
      gin += dot4f(xv, win[q]);
      ghr += dot4f(hv, whr[q]);
      ghz += dot4f(hv, whz[q]);
      ghn += dot4f(hv, whn[q]);
    }
    float r = sigm(gir + ghr), z = sigm(giz + ghz);
    float n = tanhf(gin + r * ghn);
    float hnew = (1.f - z) * n + z * hs[bl][c];
    hout[(size_t)b * 300 + c] = hnew;
    if (houtT) houtT[(size_t)c * 64 + b] = hnew;
  }
}

// ---------------- logits + fused per-block argmax partials.
// grid (125, 2): thread v-column, 32 batches; bests[125][64] packed u64.
__global__ __launch_bounds__(256) void k_dec_out(const float* __restrict__ embT,
                                                 const float* __restrict__ h1T,
                                                 const float* __restrict__ outb,
                                                 float* __restrict__ out,
                                                 unsigned long long* __restrict__ bests) {
  const int tid = threadIdx.x;
  const int v = blockIdx.x * 256 + tid;
  const int bh = blockIdx.y;
  const float* h = h1T + bh * 32;
  __shared__ float accs[32][257];
  __shared__ unsigned long long red[256];
  float acc[32];
#pragma unroll
  for (int i = 0; i < 32; ++i) acc[i] = 0.f;
  for (int k = 0; k < 300; ++k) {
    float ev = embT[(size_t)k * 32000 + v];
#pragma unroll
    for (int i = 0; i < 32; ++i) acc[i] += ev * h[(size_t)k * 64 + i];
  }
  float bo = outb[v];
#pragma unroll
  for (int i = 0; i < 32; ++i) {
    float val = acc[i] + bo;
    out[(size_t)(bh * 32 + i) * 32000 + v] = val;
    accs[i][tid] = val;
  }
  __syncthreads();
  // rows: thread (i2 = tid>>3) scans 32 columns (j = tid&7)
  const int i2 = tid >> 3, j = tid & 7;
  unsigned long long best = 0ULL;
  for (int k = 0; k < 32; ++k) {
    int cc = (j << 5) | k;
    best = umax64(best, packmax(accs[i2][cc], (blockIdx.x << 8) | cc));
  }
  red[tid] = best;
  __syncthreads();
  if (tid < 32) {
    unsigned long long m = red[tid << 3];
#pragma unroll
    for (int k = 1; k < 8; ++k) m = umax64(m, red[(tid << 3) | k]);
    bests[(size_t)blockIdx.x * 64 + (bh << 5) + tid] = m;
  }
}

extern "C" void kernel_launch(void* const* d_in, const int* in_sizes, int n_in,
                              void* d_out_v, int out_size, void* d_ws, size_t ws_size,
                              hipStream_t stream) {
  (void)in_sizes; (void)n_in; (void)out_size; (void)ws_size;
  const float* emb_enc = (const float*)d_in[0];
  const float* eWih0   = (const float*)d_in[1];
  const float* eWhh0   = (const float*)d_in[2];
  const float* ebih0   = (const float*)d_in[3];
  const float* ebhh0   = (const float*)d_in[4];
  const float* eWih1   = (const float*)d_in[5];
  const float* eWhh1   = (const float*)d_in[6];
  const float* ebih1   = (const float*)d_in[7];
  const float* ebhh1   = (const float*)d_in[8];
  const float* Wout    = (const float*)d_in[9];
  const float* emb_dec = (const float*)d_in[10];
  const float* dWih    = (const float*)d_in[11];
  const float* dWhh    = (const float*)d_in[12];
  const float* dbih    = (const float*)d_in[13];
  const float* dbhh    = (const float*)d_in[14];
  const float* W1      = (const float*)d_in[15];
  const float* l2W     = (const float*)d_in[16];
  const float* l2b     = (const float*)d_in[17];
  const float* l3W     = (const float*)d_in[18];
  const float* l3b     = (const float*)d_in[19];
  const float* Vatt    = (const float*)d_in[20];
  const float* outb    = (const float*)d_in[21];
  const int* inp       = (const int*)d_in[22];
  float* d_out = (float*)d_out_v;

  // ---- workspace carve
  float* ws = (float*)d_ws;
  size_t off = 0;
  auto take = [&](size_t n) { float* p = ws + off; off += (n + 3) & ~(size_t)3; return p; };
  float* embT   = take((size_t)300 * 32000);
  float* encout = take((size_t)8192 * 512);
  float* w1e    = take((size_t)8192 * 300);
  float* W1T    = take((size_t)300 * 512);
  float* hcat   = take((size_t)128 * 512);
  float* dech   = take((size_t)2 * 2 * 64 * 300);
  float* h1T    = take((size_t)300 * 64);
  float* xdec   = take((size_t)64 * 300);
  float* hbuf   = take((size_t)2 * 2 * 64 * 256);   // [pp][dir][64][256]
  unsigned long long* bests = (unsigned long long*)take((size_t)125 * 64 * 2);
  int* bar      = (int*)take((size_t)2 * 8 * 128);

  // ---- encoder scratch in d_out (dead before decoder writes)
  float* emb  = d_out;
  float* gi0f = emb + 2457600;
  float* gi0b = gi0f + 6291456;
  float* x1   = gi0b + 6291456;
  float* gi1f = x1 + 4194304;
  float* gi1b = gi1f + 6291456;

  hipMemsetAsync(bar, 0, 2 * 8 * 128 * sizeof(int), stream);

  k_embed<<<2400, 256, 0, stream>>>((const float4*)emb_enc, inp, (float4*)emb);
  k_transpose<<<dim3(10, 16), 256, 0, stream>>>(W1, W1T, 512, 300);
  k_transpose<<<dim3(10, 1000), 256, 0, stream>>>(emb_dec, embT, 32000, 300);

  // encoder layer 0
  k_gemm128<<<dim3(64, 6), 256, 0, stream>>>(emb, eWih0, ebih0, gi0f, 8192, 768, 300);
  k_gemm128<<<dim3(64, 6), 256, 0, stream>>>(emb, eWih0 + 230400, ebih0 + 768, gi0b, 8192, 768, 300);
  hipMemsetAsync(hbuf, 0, 2 * 2 * 64 * 256 * sizeof(float), stream);
  k_enc_layer<<<dim3(16, 4, 2), 256, 0, stream>>>(gi0f, gi0b, eWhh0, ebhh0, x1, hbuf, bar);

  // encoder layer 1
  k_gemm128<<<dim3(64, 6), 256, 0, stream>>>(x1, eWih1, ebih1, gi1f, 8192, 768, 512);
  k_gemm128<<<dim3(64, 6), 256, 0, stream>>>(x1, eWih1 + 393216, ebih1 + 768, gi1b, 8192, 768, 512);
  hipMemsetAsync(hbuf, 0, 2 * 2 * 64 * 256 * sizeof(float), stream);
  k_enc_layer<<<dim3(16, 4, 2), 256, 0, stream>>>(gi1f, gi1b, eWhh1, ebhh1, encout, hbuf, bar + 1024);

  // encoder epilogue
  k_hcat<<<256, 256, 0, stream>>>(x1, encout, hcat);
  k_gemm128<<<dim3(1, 3), 256, 0, stream>>>(hcat, Wout, nullptr, dech, 128, 300, 512);
  k_gemm128<<<dim3(64, 3), 256, 0, stream>>>(encout, W1T, nullptr, w1e, 8192, 300, 512);

  // decoder
  for (int t = 0; t < 32; ++t) {
    int cur = t & 1, nxt = cur ^ 1;
    float* hc = dech + cur * 38400;
    float* hn = dech + nxt * 38400;
    k_dec_att<<<64, 256, 0, stream>>>(hc + 19200, w1e, encout, l2W, l2b, l3W, l3b,
                                      Vatt, emb_dec, t ? bests : nullptr, xdec);
    k_gru300<<<dim3(19, 4), 256, 0, stream>>>(xdec, hc, hn, nullptr,
                                              dWih, dWhh, dbih, dbhh);
    k_gru300<<<dim3(19, 4), 256, 0, stream>>>(hn, hc + 19200, hn + 19200, h1T,
                                              dWih + 270000, dWhh + 270000,
                                              dbih + 900, dbhh + 900);
    k_dec_out<<<dim3(125, 2), 256, 0, stream>>>(embT, h1T, outb,
                                                d_out + (size_t)t * 2048000, bests);
  }
}